// Round 6
// baseline (764.686 us; speedup 1.0000x reference)
//
#include <hip/hip_runtime.h>
#include <math.h>

#define DIM 300
#define NN 127
#define KP 320
#define MATSZ (KP*KP)          // 102400 shorts per weight matrix
#define RBSZ 10240             // shorts per 32-row fragment block (32 rows x 320 k)
#define SZH 10321920           // shorts per hF stream (1008 row-blocks x RBSZ)

typedef short bf16x8 __attribute__((ext_vector_type(8)));
typedef float f32x16 __attribute__((ext_vector_type(16)));

__device__ __forceinline__ unsigned short f2bf(float f){
    unsigned u = __float_as_uint(f);
    u += 0x7fffu + ((u >> 16) & 1u);
    return (unsigned short)(u >> 16);
}
__device__ __forceinline__ float sigf(float v){ return 1.0f/(1.0f+__expf(-v)); }
__device__ __forceinline__ float tanh_(float v){
    float t = __expf(-2.0f*fabsf(v));
    float r = (1.0f - t)/(1.0f + t);
    return v < 0.0f ? -r : r;
}

#define MFMA __builtin_amdgcn_mfma_f32_32x32x16_bf16

// Fragment layout (validated round 5): 32-row x 320-k panel = RBSZ shorts:
//   addr = rb*RBSZ + ks*1024 + kk*512 + half*256 + row*8 + e ; lane reads lane*8.

__global__ void prep_weights(const float* __restrict__ Wioux,
                             const float* __restrict__ Wiouh,
                             const float* __restrict__ Wfx,
                             const float* __restrict__ Wfh,
                             unsigned short* __restrict__ WTF)
{
    int k = threadIdx.x, n = blockIdx.x, m = blockIdx.y;
    float v = 0.f;
    if (k < DIM && n < DIM){
        if (m < 3)       v = Wioux[k*(3*DIM) + m*DIM + n];
        else if (m < 6)  v = Wiouh[k*(3*DIM) + (m-3)*DIM + n];
        else if (m == 6) v = Wfx[k*DIM + n];
        else             v = Wfh[k*DIM + n];
    }
    int dst = m*MATSZ + (n>>5)*RBSZ + (k>>5)*1024 + ((k>>4)&1)*512
            + (((k>>3)&1)*32 + (n&31))*8 + (k&7);
    WTF[dst] = f2bf(v);
}

__global__ void prep_x(const float* __restrict__ x, unsigned short* __restrict__ xF)
{
    int id = blockIdx.x;                 // b*127+j
    int b = id / NN, j = id - b*NN;
    int lev = 31 - __clz(j + 1);
    int lo = (1 << lev) - 1;
    int r = b*(1 << lev) + (j - lo);
    int rb32 = 16*lo + (r >> 5), ri = r & 31;
    int t = threadIdx.x;                 // 0..319
    float v = (t < DIM) ? x[id*DIM + t] : 0.f;
    xF[rb32*RBSZ + (t>>5)*1024 + ((t>>4)&1)*512 + (((t>>3)&1)*32 + ri)*8 + (t&7)] = f2bf(v);
}

// ==================== leaf level (prefetched, no LDS) ====================
__global__ __launch_bounds__(256,3)
void leaf_mfma(const unsigned short* __restrict__ xF,
               const unsigned short* __restrict__ WTF,
               const float* __restrict__ bioux, const float* __restrict__ biouh,
               float* __restrict__ H, float* __restrict__ C,
               unsigned short* __restrict__ hF)
{
    const int t = threadIdx.x, lane = t & 63, wave = t >> 6;
    const int wm = wave >> 1, wn = wave & 1;
    const int grow0 = blockIdx.x*64 + wm*32;
    const int d0 = blockIdx.y*64 + wn*32;

    const unsigned short* ap = xF + (16*63 + (grow0 >> 5))*RBSZ + lane*8;
    const unsigned short* bp = WTF + (d0 >> 5)*RBSZ + lane*8;

    f32x16 aI, aO, aU;
    #pragma unroll
    for (int q = 0; q < 16; q++){ aI[q]=0.f; aO[q]=0.f; aU[q]=0.f; }

    bf16x8 Af[2]; bf16x8 Bf[2][3];
    auto loadstep = [&](int buf, int s){
        const int off = (s>>1)*1024 + (s&1)*512;
        Af[buf] = *(const bf16x8*)(ap + off);
        #pragma unroll
        for (int m = 0; m < 3; m++)
            Bf[buf][m] = *(const bf16x8*)(bp + m*MATSZ + off);
    };
    loadstep(0,0); loadstep(1,1);
    #pragma unroll
    for (int s = 0; s < 20; s++){
        const int cb = s & 1;
        aI = MFMA(Af[cb], Bf[cb][0], aI, 0, 0, 0);
        aO = MFMA(Af[cb], Bf[cb][1], aO, 0, 0, 0);
        aU = MFMA(Af[cb], Bf[cb][2], aU, 0, 0, 0);
        if (s < 18) loadstep(cb, s+2);
    }
    int d = d0 + (lane & 31);
    if (d < DIM){
        float bi  = bioux[d]       + biouh[d];
        float bo_ = bioux[DIM+d]   + biouh[DIM+d];
        float bu  = bioux[2*DIM+d] + biouh[2*DIM+d];
        #pragma unroll
        for (int q = 0; q < 16; q++){
            int grow = grow0 + (q&3) + 8*(q>>2) + 4*(lane>>5);
            int b = grow >> 6, j = 63 + (grow & 63);
            int nb = b*NN + j;
            float iv = sigf (aI[q] + bi);
            float ov = sigf (aO[q] + bo_);
            float uv = tanh_(aU[q] + bu);
            float cv = iv*uv;
            float hv = ov*tanh_(cv);
            C[nb*DIM + d] = cv;
            H[nb*DIM + d] = hv;
            int jp = (j - 1) >> 1, s2 = 1 - (j & 1);
            int rp = b*32 + (jp - 31);
            int dst = s2*SZH + (16*31 + (rp>>5))*RBSZ + (d>>5)*1024 + ((d>>4)&1)*512
                    + (((d>>3)&1)*32 + (rp&31))*8 + (d&7);
            hF[dst] = f2bf(hv);
        }
    }
}

// ==================== internal-level body (prefetched) ====================
__device__ __forceinline__ void level_body(
    int bx, int by, int lshift,
    const unsigned short* __restrict__ xF, const unsigned short* __restrict__ hF,
    const unsigned short* __restrict__ WTF,
    const float* __restrict__ bioux, const float* __restrict__ biouh,
    const float* __restrict__ bfx,   const float* __restrict__ bfh,
    float* __restrict__ H, float* __restrict__ C,
    unsigned short* __restrict__ hFw,
    int lane, int wave)
{
    const int wm = wave >> 1, wn = wave & 1;
    const int grow0 = bx*64 + wm*32;
    const int d0 = by*64 + wn*32;
    const int lo = (1 << lshift) - 1;

    const int base32 = 16*lo + (grow0 >> 5);
    const unsigned short* ap  = xF + base32*RBSZ + lane*8;
    const unsigned short* h0p = hF + base32*RBSZ + lane*8;
    const unsigned short* h1p = h0p + SZH;
    const unsigned short* bp  = WTF + (d0 >> 5)*RBSZ + lane*8;

    f32x16 aI, aO, aU, aF0, aF1;
    #pragma unroll
    for (int q = 0; q < 16; q++){
        aI[q]=0.f; aO[q]=0.f; aU[q]=0.f; aF0[q]=0.f; aF1[q]=0.f;
    }

    bf16x8 Af[2][3]; bf16x8 Bf[2][8];
    auto loadstep = [&](int buf, int s){
        const int off = (s>>1)*1024 + (s&1)*512;
        Af[buf][0] = *(const bf16x8*)(ap  + off);
        Af[buf][1] = *(const bf16x8*)(h0p + off);
        Af[buf][2] = *(const bf16x8*)(h1p + off);
        #pragma unroll
        for (int m = 0; m < 8; m++)
            Bf[buf][m] = *(const bf16x8*)(bp + m*MATSZ + off);
    };
    loadstep(0,0); loadstep(1,1);
    #pragma unroll
    for (int s = 0; s < 20; s++){
        const int cb = s & 1;
        aI  = MFMA(Af[cb][0], Bf[cb][0], aI , 0, 0, 0);
        aI  = MFMA(Af[cb][1], Bf[cb][3], aI , 0, 0, 0);
        aI  = MFMA(Af[cb][2], Bf[cb][3], aI , 0, 0, 0);
        aO  = MFMA(Af[cb][0], Bf[cb][1], aO , 0, 0, 0);
        aO  = MFMA(Af[cb][1], Bf[cb][4], aO , 0, 0, 0);
        aO  = MFMA(Af[cb][2], Bf[cb][4], aO , 0, 0, 0);
        aU  = MFMA(Af[cb][0], Bf[cb][2], aU , 0, 0, 0);
        aU  = MFMA(Af[cb][1], Bf[cb][5], aU , 0, 0, 0);
        aU  = MFMA(Af[cb][2], Bf[cb][5], aU , 0, 0, 0);
        aF0 = MFMA(Af[cb][0], Bf[cb][6], aF0, 0, 0, 0);
        aF0 = MFMA(Af[cb][1], Bf[cb][7], aF0, 0, 0, 0);
        aF1 = MFMA(Af[cb][0], Bf[cb][6], aF1, 0, 0, 0);
        aF1 = MFMA(Af[cb][2], Bf[cb][7], aF1, 0, 0, 0);
        if (s < 18) loadstep(cb, s+2);
    }
    int d = d0 + (lane & 31);
    if (d < DIM){
        float bi  = bioux[d]       + biouh[d];
        float bo_ = bioux[DIM+d]   + biouh[DIM+d];
        float bu  = bioux[2*DIM+d] + biouh[2*DIM+d];
        float bf_ = bfx[d] + bfh[d];
        #pragma unroll
        for (int q = 0; q < 16; q++){
            int grow = grow0 + (q&3) + 8*(q>>2) + 4*(lane>>5);
            int b = grow >> lshift, j = lo + (grow & lo);
            int nb = b*NN + j;
            float c0 = C[(b*NN + 2*j+1)*DIM + d];
            float c1 = C[(b*NN + 2*j+2)*DIM + d];
            float iv = sigf (aI[q] + bi);
            float ov = sigf (aO[q] + bo_);
            float uv = tanh_(aU[q] + bu);
            float f0 = sigf (aF0[q] + bf_);
            float f1 = sigf (aF1[q] + bf_);
            float cv = iv*uv + f0*c0 + f1*c1;
            float hv = ov*tanh_(cv);
            C[nb*DIM + d] = cv;
            H[nb*DIM + d] = hv;
            if (lshift > 0){
                int jp = (j - 1) >> 1, s2 = 1 - (j & 1);
                int lop = (1 << (lshift-1)) - 1;
                int rp = b*(1 << (lshift-1)) + (jp - lop);
                int dst = s2*SZH + (16*lop + (rp>>5))*RBSZ + (d>>5)*1024 + ((d>>4)&1)*512
                        + (((d>>3)&1)*32 + (rp&31))*8 + (d&7);
                hFw[dst] = f2bf(hv);
            }
        }
    }
}

__global__ __launch_bounds__(256,2)
void level_mfma(const unsigned short* __restrict__ xF,
                const unsigned short* __restrict__ hF,
                const unsigned short* __restrict__ WTF,
                const float* __restrict__ bioux, const float* __restrict__ biouh,
                const float* __restrict__ bfx,   const float* __restrict__ bfh,
                float* __restrict__ H, float* __restrict__ C,
                unsigned short* __restrict__ hFw,
                int lshift)
{
    const int t = threadIdx.x;
    level_body(blockIdx.x, blockIdx.y, lshift, xF, hF, WTF,
               bioux, biouh, bfx, bfh, H, C, hFw, t & 63, t >> 6);
}

// ==================== fused tail: levels 3..0, persistent, global barrier ====================
__global__ __launch_bounds__(256,2)
void tail_mfma(const unsigned short* __restrict__ xF,
               const unsigned short* __restrict__ hF,
               const unsigned short* __restrict__ WTF,
               const float* __restrict__ bioux, const float* __restrict__ biouh,
               const float* __restrict__ bfx,   const float* __restrict__ bfh,
               float* __restrict__ H, float* __restrict__ C,
               unsigned short* __restrict__ hFw,
               unsigned int* bar)
{
    const int t = threadIdx.x;
    const int lane = t & 63, wave = t >> 6;
    int phase = 0;
    for (int l = 3; l >= 0; l--){
        const int nx = 8 << l;
        if ((int)blockIdx.x < nx*5){
            int bx = blockIdx.x % nx, by = blockIdx.x / nx;
            level_body(bx, by, l, xF, hF, WTF, bioux, biouh, bfx, bfh,
                       H, C, hFw, lane, wave);
        }
        if (l > 0){
            // device-wide barrier across all 320 co-resident blocks
            __threadfence();
            __syncthreads();
            if (t == 0){
                atomicAdd(bar, 1u);
                unsigned target = 320u * (unsigned)(phase + 1);
                while (atomicAdd(bar, 0u) < target){
                    __builtin_amdgcn_s_sleep(8);
                }
            }
            __syncthreads();
            __threadfence();
            phase++;
        }
    }
}

extern "C" void kernel_launch(void* const* d_in, const int* in_sizes, int n_in,
                              void* d_out, int out_size, void* d_ws, size_t ws_size,
                              hipStream_t stream) {
    const float* x     = (const float*)d_in[0];
    const float* Wioux = (const float*)d_in[1];
    const float* bioux = (const float*)d_in[2];
    const float* Wiouh = (const float*)d_in[3];
    const float* biouh = (const float*)d_in[4];
    const float* Wfx   = (const float*)d_in[5];
    const float* bfx   = (const float*)d_in[6];
    const float* Wfh   = (const float*)d_in[7];
    const float* bfh   = (const float*)d_in[8];
    float* H = (float*)d_out;
    // ws: C fp32 78,028,800 | WTF 1,638,400 | xF 41,615,360 | hF 41,287,680 | bar 4
    float* C = (float*)d_ws;
    unsigned short* WTF = (unsigned short*)((char*)d_ws + 78028800);
    unsigned short* xF  = (unsigned short*)((char*)d_ws + 79667200);
    unsigned short* hF  = (unsigned short*)((char*)d_ws + 121282560);
    unsigned int*   bar = (unsigned int*)((char*)d_ws + 162570240);

    hipMemsetAsync(bar, 0, 4, stream);
    prep_weights<<<dim3(KP, 8), KP, 0, stream>>>(Wioux, Wiouh, Wfx, Wfh, WTF);
    prep_x<<<dim3(512*NN), KP, 0, stream>>>(x, xF);
    leaf_mfma<<<dim3(512, 5), 256, 0, stream>>>(xF, WTF, bioux, biouh, H, C, hF);
    for (int l = 5; l >= 4; l--){
        level_mfma<<<dim3(8 << l, 5), 256, 0, stream>>>(
            xF, hF, WTF, bioux, biouh, bfx, bfh, H, C, hF, l);
    }
    tail_mfma<<<dim3(320), 256, 0, stream>>>(
        xF, hF, WTF, bioux, biouh, bfx, bfh, H, C, hF, bar);
}